// Round 6
// baseline (507.674 us; speedup 1.0000x reference)
//
#include <hip/hip_runtime.h>
#include <hip/hip_bf16.h>
#include <stdint.h>

typedef __hip_bfloat16 bf16;
typedef __hip_bfloat162 bf162;

typedef __attribute__((ext_vector_type(8))) short short8;   // 8 bf16 = 4 VGPRs
typedef __attribute__((ext_vector_type(4))) float floatx4;  // MFMA accumulator

#define BSH   8        // bucket = 256 nodes
#define BSZ   256
#define CHUNK 8192     // edges per sort block
#define NBMAX 512      // max buckets supported (N <= 131072)
#define ASTRIDE 136    // LDS A-tile row stride in bf16 (272 B)

// ---------------- helpers ----------------

__device__ __forceinline__ float2 load2f(const bf16* __restrict__ p) {
    const unsigned int u = *(const unsigned int*)p;
    return make_float2(__uint_as_float((u & 0xffffu) << 16),
                       __uint_as_float(u & 0xffff0000u));
}

// ---------------- prep: fp32 -> bf16 ----------------

__global__ __launch_bounds__(256)
void cvt_kernel(const float* __restrict__ x, bf16* __restrict__ y, int n4) {
    int i = blockIdx.x * 256 + threadIdx.x;
    if (i < n4) {
        float4 v = ((const float4*)x)[i];
        bf162 a, b;
        a.x = __float2bfloat16(v.x); a.y = __float2bfloat16(v.y);
        b.x = __float2bfloat16(v.z); b.y = __float2bfloat16(v.w);
        ((bf162*)y)[i * 2]     = a;
        ((bf162*)y)[i * 2 + 1] = b;
    }
}

// weights pre-swizzled to B-fragment layout for mfma_f32_16x16x32_bf16:
// wsw[((kt*8+ct)*64+lane)*8 + j] = W[kt*32 + (lane>>4)*8 + j][ct*16 + (lane&15)]
// where W = concat_k(w_rel, w_root), 256x128 row-major.
__global__ __launch_bounds__(256)
void prep_w_kernel(const float* __restrict__ wrel, const float* __restrict__ wroot,
                   bf16* __restrict__ wsw) {
    int t = blockIdx.x * 256 + threadIdx.x;       // 0..4095
    if (t >= 4096) return;
    const int lane = t & 63;
    const int ct   = (t >> 6) & 7;
    const int kt   = t >> 9;
    const int kbase = kt * 32 + (lane >> 4) * 8;
    const int n     = ct * 16 + (lane & 15);
    bf16* q = wsw + (size_t)t * 8;
#pragma unroll
    for (int j = 0; j < 8; ++j) {
        const int k = kbase + j;
        const float v = (k < 128) ? wrel[k * 128 + n] : wroot[(k - 128) * 128 + n];
        q[j] = __float2bfloat16(v);
    }
}

// ---------------- CSR build: two-level counting sort ----------------

__global__ __launch_bounds__(256)
void bhist_kernel(const int* __restrict__ dst, int* __restrict__ T,
                  int E, int NB, int GB) {
    __shared__ int lh[NBMAX];
    const int b = blockIdx.x;
    for (int u = threadIdx.x; u < NB; u += 256) lh[u] = 0;
    __syncthreads();
    const int beg = b * CHUNK, end = min(beg + CHUNK, E);
    for (int e = beg + threadIdx.x; e < end; e += 256)
        atomicAdd(&lh[dst[e] >> BSH], 1);
    __syncthreads();
    for (int u = threadIdx.x; u < NB; u += 256)
        T[u * GB + b] = lh[u];
}

__global__ __launch_bounds__(256)
void scan1_kernel(const int* __restrict__ deg, int* __restrict__ rp,
                  int* __restrict__ bsum, int n) {
    __shared__ int s[256];
    const int tid = threadIdx.x;
    const int i = blockIdx.x * 256 + tid;
    const int d = (i < n) ? deg[i] : 0;
    s[tid] = d;
    __syncthreads();
    for (int off = 1; off < 256; off <<= 1) {
        int u = (tid >= off) ? s[tid - off] : 0;
        __syncthreads();
        s[tid] += u;
        __syncthreads();
    }
    if (i < n) rp[i] = s[tid] - d;
    if (tid == 255) bsum[blockIdx.x] = s[255];
}

__global__ __launch_bounds__(512)
void scan2_kernel(int* __restrict__ bsum, int G) {
    __shared__ int s[512];
    const int tid = threadIdx.x;
    const int d = (tid < G) ? bsum[tid] : 0;
    s[tid] = d;
    __syncthreads();
    for (int off = 1; off < 512; off <<= 1) {
        int u = (tid >= off) ? s[tid - off] : 0;
        __syncthreads();
        s[tid] += u;
        __syncthreads();
    }
    if (tid < G) bsum[tid] = s[tid] - d;
}

__global__ __launch_bounds__(256)
void scan3_kernel(int* __restrict__ rp, const int* __restrict__ bsum, int n) {
    const int i = blockIdx.x * 256 + threadIdx.x;
    if (i < n) rp[i] += bsum[blockIdx.x];
}

__global__ __launch_bounds__(256)
void bscatter_kernel(const int* __restrict__ src, const int* __restrict__ dst,
                     const int* __restrict__ T, int* __restrict__ ebuf,
                     int E, int NB, int GB) {
    __shared__ int lofs[NBMAX];
    const int b = blockIdx.x;
    for (int u = threadIdx.x; u < NB; u += 256)
        lofs[u] = T[u * GB + b];
    __syncthreads();
    const int beg = b * CHUNK, end = min(beg + CHUNK, E);
    for (int e = beg + threadIdx.x; e < end; e += 256) {
        const int d = dst[e];
        const int u = d >> BSH;
        const int pos = atomicAdd(&lofs[u], 1);
        ebuf[pos] = (src[e] << BSH) | (d & (BSZ - 1));
    }
}

__global__ __launch_bounds__(256)
void bbuild_kernel(const int* __restrict__ T, const int* __restrict__ ebuf,
                   int* __restrict__ rp, int* __restrict__ col,
                   int E, int N, int NB, int GB) {
    __shared__ int s[256];
    __shared__ int lrank[256];
    const int u = blockIdx.x;
    const int tid = threadIdx.x;
    const int beg = T[u * GB];
    const int end = (u + 1 < NB) ? T[(u + 1) * GB] : E;

    lrank[tid] = 0;
    __syncthreads();
    for (int e = beg + tid; e < end; e += 256)
        atomicAdd(&lrank[ebuf[e] & (BSZ - 1)], 1);
    __syncthreads();
    const int cntv = lrank[tid];
    s[tid] = cntv;
    __syncthreads();
    for (int off = 1; off < 256; off <<= 1) {
        int v = (tid >= off) ? s[tid - off] : 0;
        __syncthreads();
        s[tid] += v;
        __syncthreads();
    }
    const int excl = s[tid] - cntv;
    const int node = u * BSZ + tid;
    if (node < N) rp[node] = beg + excl;
    if (u == NB - 1 && tid == 0) rp[N] = E;
    lrank[tid] = beg + excl;
    __syncthreads();
    for (int e = beg + tid; e < end; e += 256) {
        const int p = ebuf[e];
        const int pos = atomicAdd(&lrank[p & (BSZ - 1)], 1);
        col[pos] = p >> BSH;
    }
}

// ---------------- fused layer: 16 waves, 1 node/wave gather -> LDS -> MFMA ----------------
// block = 1024 threads = 16 waves = 16 nodes (full gather wave-parallelism:
// one wave per node, identical to the split agg kernel).
// phase 1: wave w aggregates node node0+w (lane owns 2 features, 8-edge unroll)
//          into LDS A-tile row w.
// phase 2: waves 0..7 compute out[16 rows x 16 cols of ct=wave] =
//          [Atile | h] @ Wsw + b (+relu); kt 0..3 A-frags from LDS,
//          kt 4..7 root-frags from global. Waves 8..15 exit after barrier.

template <bool RELU, typename OT>
__global__ __launch_bounds__(1024, 4)
void fused_layer_kernel(const bf16* __restrict__ h, const int* __restrict__ rp,
                        const int* __restrict__ col, const bf16* __restrict__ wsw,
                        const float* __restrict__ bias, OT* __restrict__ out, int N) {
    __shared__ bf16 As[16 * ASTRIDE];
    const int tid  = threadIdx.x;
    const int lane = tid & 63;
    const int wave = tid >> 6;            // 0..15
    const int node0 = blockIdx.x * 16;
    const int node  = node0 + wave;
    const int f = lane * 2;

    // ---- phase 1: gather (1 node per wave, zero divergence) ----
    float2 acc2 = make_float2(0.f, 0.f);
    if (node < N) {
        const int beg = rp[node], end = rp[node + 1];
        int e = beg;
        for (; e + 8 <= end; e += 8) {
            const int s0 = col[e],     s1 = col[e + 1], s2 = col[e + 2], s3 = col[e + 3];
            const int s4 = col[e + 4], s5 = col[e + 5], s6 = col[e + 6], s7 = col[e + 7];
            const float2 a0 = load2f(h + (size_t)s0 * 128 + f);
            const float2 a1 = load2f(h + (size_t)s1 * 128 + f);
            const float2 a2 = load2f(h + (size_t)s2 * 128 + f);
            const float2 a3 = load2f(h + (size_t)s3 * 128 + f);
            const float2 a4 = load2f(h + (size_t)s4 * 128 + f);
            const float2 a5 = load2f(h + (size_t)s5 * 128 + f);
            const float2 a6 = load2f(h + (size_t)s6 * 128 + f);
            const float2 a7 = load2f(h + (size_t)s7 * 128 + f);
            acc2.x += ((a0.x + a1.x) + (a2.x + a3.x)) + ((a4.x + a5.x) + (a6.x + a7.x));
            acc2.y += ((a0.y + a1.y) + (a2.y + a3.y)) + ((a4.y + a5.y) + (a6.y + a7.y));
        }
        for (; e + 2 <= end; e += 2) {
            const int s0 = col[e], s1 = col[e + 1];
            const float2 a0 = load2f(h + (size_t)s0 * 128 + f);
            const float2 a1 = load2f(h + (size_t)s1 * 128 + f);
            acc2.x += a0.x + a1.x;
            acc2.y += a0.y + a1.y;
        }
        if (e < end) {
            const float2 a0 = load2f(h + (size_t)col[e] * 128 + f);
            acc2.x += a0.x;
            acc2.y += a0.y;
        }
    }
    bf162 o;
    o.x = __float2bfloat16(acc2.x);
    o.y = __float2bfloat16(acc2.y);
    *(bf162*)(As + wave * ASTRIDE + f) = o;
    __syncthreads();

    // ---- phase 2: dual GEMM on waves 0..7 (ct = wave) ----
    if (wave >= 8) return;
    const int l15  = lane & 15;
    const int quad = lane >> 4;
    const int ct   = wave;

    floatx4 acc = (floatx4){0.f, 0.f, 0.f, 0.f};

    // neighbor half: A-frags from LDS
#pragma unroll
    for (int kt = 0; kt < 4; ++kt) {
        const short8 afrag = *(const short8*)(As + l15 * ASTRIDE + kt * 32 + quad * 8);
        const short8 bfrag = *(const short8*)(wsw + (size_t)((kt * 8 + ct) * 64 + lane) * 8);
        acc = __builtin_amdgcn_mfma_f32_16x16x32_bf16(afrag, bfrag, acc, 0, 0, 0);
    }
    // root half: A-frags from global h
    const int row_a = node0 + l15;
    const bool rowok = row_a < N;
#pragma unroll
    for (int kt = 4; kt < 8; ++kt) {
        short8 afrag = (short8){0, 0, 0, 0, 0, 0, 0, 0};
        if (rowok)
            afrag = *(const short8*)(h + (size_t)row_a * 128 + (kt - 4) * 32 + quad * 8);
        const short8 bfrag = *(const short8*)(wsw + (size_t)((kt * 8 + ct) * 64 + lane) * 8);
        acc = __builtin_amdgcn_mfma_f32_16x16x32_bf16(afrag, bfrag, acc, 0, 0, 0);
    }

    const int colc = ct * 16 + l15;
    const float bv = bias[colc];
    const int row_o = node0 + quad * 4;
#pragma unroll
    for (int r = 0; r < 4; ++r) {
        const int row = row_o + r;
        if (row < N) {
            float v = acc[r] + bv;
            if (RELU) v = fmaxf(v, 0.f);
            if constexpr (sizeof(OT) == 2)
                ((bf16*)out)[(size_t)row * 128 + colc] = __float2bfloat16(v);
            else
                ((float*)out)[(size_t)row * 128 + colc] = v;
        }
    }
}

// ---------------- launch ----------------

extern "C" void kernel_launch(void* const* d_in, const int* in_sizes, int n_in,
                              void* d_out, int out_size, void* d_ws, size_t ws_size,
                              hipStream_t stream) {
    const float* x       = (const float*)d_in[0];
    const int*   ei      = (const int*)d_in[1];
    const float* w_rel1  = (const float*)d_in[2];
    const float* w_root1 = (const float*)d_in[3];
    const float* b1      = (const float*)d_in[4];
    const float* w_rel2  = (const float*)d_in[5];
    const float* w_root2 = (const float*)d_in[6];
    const float* b2      = (const float*)d_in[7];
    const float* w_rel3  = (const float*)d_in[8];
    const float* w_root3 = (const float*)d_in[9];
    const float* b3      = (const float*)d_in[10];
    float* out = (float*)d_out;

    const int N = in_sizes[0] / 128;
    const int E = in_sizes[1] / 2;
    const int* src = ei;
    const int* dst = ei + E;

    // workspace layout (~65 MB)
    char* w = (char*)d_ws;
    auto alloc = [&](size_t bytes) {
        char* p = w;
        w += (bytes + 255) & ~(size_t)255;
        return p;
    };
    int*  col  = (int*)alloc((size_t)E * 4);            // 6.4 MB
    int*  rp   = (int*)alloc((size_t)(N + 1) * 4);      // 0.4 MB
    int*  ebuf = (int*)alloc((size_t)E * 4);            // 6.4 MB
    bf16* h1   = (bf16*)alloc((size_t)N * 128 * 2);     // 25.6 MB
    bf16* xbf  = (bf16*)alloc((size_t)N * 128 * 2);     // 25.6 MB (reused as h2)
    bf16* wsw1 = (bf16*)alloc(32768 * 2);               // 64 KB
    bf16* wsw2 = (bf16*)alloc(32768 * 2);
    bf16* wsw3 = (bf16*)alloc(32768 * 2);
    bf16* h2   = xbf;   // layer-2 output overwrites xbf (last read: layer-1 fused)
    // CSR-build scratch aliases h1 (written only after the build completes):
    int*  T    = (int*)h1;                  // NB*GB ints (~306 KB)
    int*  bsum = (int*)(h1 + 1024 * 1024);  // scan partials, past T

    const int NB = (N + BSZ - 1) / BSZ;        // 391 buckets
    const int GB = (E + CHUNK - 1) / CHUNK;    // 196 sort blocks
    const int nT = NB * GB;                    // 76,636
    const int scanTBlocks = (nT + 255) / 256;  // 300 <= 512

    const int layerBlocks = (N + 15) / 16;     // 6250 blocks x 1024 threads
    const int cvtBlocks   = (N * 32 + 255) / 256;

    // prep: x -> bf16, weights -> swizzled bf16 B-fragments
    cvt_kernel<<<cvtBlocks, 256, 0, stream>>>(x, xbf, N * 32);
    prep_w_kernel<<<16, 256, 0, stream>>>(w_rel1, w_root1, wsw1);
    prep_w_kernel<<<16, 256, 0, stream>>>(w_rel2, w_root2, wsw2);
    prep_w_kernel<<<16, 256, 0, stream>>>(w_rel3, w_root3, wsw3);

    // CSR by dst: two-level counting sort (no global atomics, no memsets)
    bhist_kernel<<<GB, 256, 0, stream>>>(dst, T, E, NB, GB);
    scan1_kernel<<<scanTBlocks, 256, 0, stream>>>(T, T, bsum, nT);
    scan2_kernel<<<1, 512, 0, stream>>>(bsum, scanTBlocks);
    scan3_kernel<<<scanTBlocks, 256, 0, stream>>>(T, bsum, nT);
    bscatter_kernel<<<GB, 256, 0, stream>>>(src, dst, T, ebuf, E, NB, GB);
    bbuild_kernel<<<NB, 256, 0, stream>>>(T, ebuf, rp, col, E, N, NB, GB);

    // fused layers (agg -> LDS -> dual MFMA GEMM, no agg round-trip)
    fused_layer_kernel<true, bf16><<<layerBlocks, 1024, 0, stream>>>(xbf, rp, col, wsw1, b1, h1, N);
    fused_layer_kernel<true, bf16><<<layerBlocks, 1024, 0, stream>>>(h1, rp, col, wsw2, b2, h2, N);
    fused_layer_kernel<false, float><<<layerBlocks, 1024, 0, stream>>>(h2, rp, col, wsw3, b3, out, N);
}

// Round 7
// 505.772 us; speedup vs baseline: 1.0038x; 1.0038x over previous
//
#include <hip/hip_runtime.h>
#include <hip/hip_bf16.h>
#include <stdint.h>

typedef __hip_bfloat16 bf16;
typedef __hip_bfloat162 bf162;

typedef __attribute__((ext_vector_type(8))) short short8;   // 8 bf16 = 4 VGPRs
typedef __attribute__((ext_vector_type(4))) float floatx4;  // MFMA accumulator

#define BSH   8        // bucket = 256 nodes
#define BSZ   256
#define CHUNK 8192     // edges per sort block
#define NBMAX 512      // max buckets supported (N <= 131072)

// ---------------- prep: fp32 -> bf16 ----------------

__global__ __launch_bounds__(256)
void cvt_kernel(const float* __restrict__ x, bf16* __restrict__ y, int n4) {
    int i = blockIdx.x * 256 + threadIdx.x;
    if (i < n4) {
        float4 v = ((const float4*)x)[i];
        bf162 a, b;
        a.x = __float2bfloat16(v.x); a.y = __float2bfloat16(v.y);
        b.x = __float2bfloat16(v.z); b.y = __float2bfloat16(v.w);
        ((bf162*)y)[i * 2]     = a;
        ((bf162*)y)[i * 2 + 1] = b;
    }
}

// weights pre-swizzled to B-fragment layout for mfma_f32_16x16x32_bf16:
// wsw[((kt*8+ct)*64+lane)*8 + j] = W[kt*32 + (lane>>4)*8 + j][ct*16 + (lane&15)]
// where W = concat_k(w_rel, w_root), 256x128 row-major.
__global__ __launch_bounds__(256)
void prep_w_kernel(const float* __restrict__ wrel, const float* __restrict__ wroot,
                   bf16* __restrict__ wsw) {
    int t = blockIdx.x * 256 + threadIdx.x;       // 0..4095
    if (t >= 4096) return;
    const int lane = t & 63;
    const int ct   = (t >> 6) & 7;
    const int kt   = t >> 9;
    const int kbase = kt * 32 + (lane >> 4) * 8;
    const int n     = ct * 16 + (lane & 15);
    bf16* q = wsw + (size_t)t * 8;
#pragma unroll
    for (int j = 0; j < 8; ++j) {
        const int k = kbase + j;
        const float v = (k < 128) ? wrel[k * 128 + n] : wroot[(k - 128) * 128 + n];
        q[j] = __float2bfloat16(v);
    }
}

// ---------------- CSR build: two-level counting sort ----------------

__global__ __launch_bounds__(256)
void bhist_kernel(const int* __restrict__ dst, int* __restrict__ T,
                  int E, int NB, int GB) {
    __shared__ int lh[NBMAX];
    const int b = blockIdx.x;
    for (int u = threadIdx.x; u < NB; u += 256) lh[u] = 0;
    __syncthreads();
    const int beg = b * CHUNK, end = min(beg + CHUNK, E);
    for (int e = beg + threadIdx.x; e < end; e += 256)
        atomicAdd(&lh[dst[e] >> BSH], 1);
    __syncthreads();
    for (int u = threadIdx.x; u < NB; u += 256)
        T[u * GB + b] = lh[u];
}

__global__ __launch_bounds__(256)
void scan1_kernel(const int* __restrict__ deg, int* __restrict__ rp,
                  int* __restrict__ bsum, int n) {
    __shared__ int s[256];
    const int tid = threadIdx.x;
    const int i = blockIdx.x * 256 + tid;
    const int d = (i < n) ? deg[i] : 0;
    s[tid] = d;
    __syncthreads();
    for (int off = 1; off < 256; off <<= 1) {
        int u = (tid >= off) ? s[tid - off] : 0;
        __syncthreads();
        s[tid] += u;
        __syncthreads();
    }
    if (i < n) rp[i] = s[tid] - d;
    if (tid == 255) bsum[blockIdx.x] = s[255];
}

__global__ __launch_bounds__(512)
void scan2_kernel(int* __restrict__ bsum, int G) {
    __shared__ int s[512];
    const int tid = threadIdx.x;
    const int d = (tid < G) ? bsum[tid] : 0;
    s[tid] = d;
    __syncthreads();
    for (int off = 1; off < 512; off <<= 1) {
        int u = (tid >= off) ? s[tid - off] : 0;
        __syncthreads();
        s[tid] += u;
        __syncthreads();
    }
    if (tid < G) bsum[tid] = s[tid] - d;
}

__global__ __launch_bounds__(256)
void scan3_kernel(int* __restrict__ rp, const int* __restrict__ bsum, int n) {
    const int i = blockIdx.x * 256 + threadIdx.x;
    if (i < n) rp[i] += bsum[blockIdx.x];
}

__global__ __launch_bounds__(256)
void bscatter_kernel(const int* __restrict__ src, const int* __restrict__ dst,
                     const int* __restrict__ T, int* __restrict__ ebuf,
                     int E, int NB, int GB) {
    __shared__ int lofs[NBMAX];
    const int b = blockIdx.x;
    for (int u = threadIdx.x; u < NB; u += 256)
        lofs[u] = T[u * GB + b];
    __syncthreads();
    const int beg = b * CHUNK, end = min(beg + CHUNK, E);
    for (int e = beg + threadIdx.x; e < end; e += 256) {
        const int d = dst[e];
        const int u = d >> BSH;
        const int pos = atomicAdd(&lofs[u], 1);
        ebuf[pos] = (src[e] << BSH) | (d & (BSZ - 1));
    }
}

__global__ __launch_bounds__(256)
void bbuild_kernel(const int* __restrict__ T, const int* __restrict__ ebuf,
                   int* __restrict__ rp, int* __restrict__ col,
                   int E, int N, int NB, int GB) {
    __shared__ int s[256];
    __shared__ int lrank[256];
    const int u = blockIdx.x;
    const int tid = threadIdx.x;
    const int beg = T[u * GB];
    const int end = (u + 1 < NB) ? T[(u + 1) * GB] : E;

    lrank[tid] = 0;
    __syncthreads();
    for (int e = beg + tid; e < end; e += 256)
        atomicAdd(&lrank[ebuf[e] & (BSZ - 1)], 1);
    __syncthreads();
    const int cntv = lrank[tid];
    s[tid] = cntv;
    __syncthreads();
    for (int off = 1; off < 256; off <<= 1) {
        int v = (tid >= off) ? s[tid - off] : 0;
        __syncthreads();
        s[tid] += v;
        __syncthreads();
    }
    const int excl = s[tid] - cntv;
    const int node = u * BSZ + tid;
    if (node < N) rp[node] = beg + excl;
    if (u == NB - 1 && tid == 0) rp[N] = E;
    lrank[tid] = beg + excl;
    __syncthreads();
    for (int e = beg + tid; e < end; e += 256) {
        const int p = ebuf[e];
        const int pos = atomicAdd(&lrank[p & (BSZ - 1)], 1);
        col[pos] = p >> BSH;
    }
}

// ---------------- aggregation (CSR, atomic-free, bf16, vectorized gather) ----------------
// one wave per node (independent retirement — no barrier coupling).
// lane l loads 16 B of row col[e + (l>>4)] at feature offset (l&15)*8:
// one instruction = 4 full rows = 1 KB. 8-group unroll = 32 edges/iter,
// 8 KB in flight per wave. Final 2-step shfl_xor butterfly merges the
// 4 lane-quads; lanes 0..15 store the 128-feature row as 16 B each.

__global__ __launch_bounds__(256)
void agg_kernel(const bf16* __restrict__ h, const int* __restrict__ rp,
                const int* __restrict__ col, bf16* __restrict__ agg, int N) {
    const int lane = threadIdx.x & 63;
    const int wid  = threadIdx.x >> 6;
    const int node = blockIdx.x * 4 + wid;
    if (node >= N) return;
    const int beg = rp[node], end = rp[node + 1];
    const int eg = lane >> 4;          // edge sub-slot 0..3
    const int fo = (lane & 15) * 8;    // 8 features = 16 B per lane

    float v[8];
#pragma unroll
    for (int j = 0; j < 8; ++j) v[j] = 0.f;

    for (int e = beg; e < end; e += 32) {
        uint4 r[8];
#pragma unroll
        for (int g = 0; g < 8; ++g) {
            r[g] = make_uint4(0u, 0u, 0u, 0u);
            const int ee = e + g * 4 + eg;
            if (ee < end) {
                const int s = col[ee];
                r[g] = *(const uint4*)(h + (size_t)s * 128 + fo);
            }
        }
#pragma unroll
        for (int g = 0; g < 8; ++g) {
            const uint4 u = r[g];
            v[0] += __uint_as_float((u.x & 0xffffu) << 16);
            v[1] += __uint_as_float(u.x & 0xffff0000u);
            v[2] += __uint_as_float((u.y & 0xffffu) << 16);
            v[3] += __uint_as_float(u.y & 0xffff0000u);
            v[4] += __uint_as_float((u.z & 0xffffu) << 16);
            v[5] += __uint_as_float(u.z & 0xffff0000u);
            v[6] += __uint_as_float((u.w & 0xffffu) << 16);
            v[7] += __uint_as_float(u.w & 0xffff0000u);
        }
    }

    // merge the 4 lane-quads (lanes l, l^16, l^32, l^48 share features fo..fo+7)
#pragma unroll
    for (int j = 0; j < 8; ++j) {
        v[j] += __shfl_xor(v[j], 16, 64);
        v[j] += __shfl_xor(v[j], 32, 64);
    }

    if (lane < 16) {
        union { short8 s8; bf16 b[8]; } o;
#pragma unroll
        for (int j = 0; j < 8; ++j) o.b[j] = __float2bfloat16(v[j]);
        *(short8*)(agg + (size_t)node * 128 + fo) = o.s8;
    }
}

// ---------------- MFMA dual GEMM: out = [agg|h] @ Wsw + b (+relu) ----------------

template <bool RELU, typename OT>
__global__ __launch_bounds__(256)
void mfma_gemm_kernel(const bf16* __restrict__ Aagg, const bf16* __restrict__ Hroot,
                      const bf16* __restrict__ wsw, const float* __restrict__ bias,
                      OT* __restrict__ out, int M) {
    const int tid  = threadIdx.x;
    const int lane = tid & 63;
    const int wave = tid >> 6;
    const int l15  = lane & 15;
    const int quad = lane >> 4;

    const int row_a = blockIdx.x * 64 + wave * 16 + l15;
    const bool rowok = row_a < M;

    floatx4 acc[8];
#pragma unroll
    for (int ct = 0; ct < 8; ++ct) acc[ct] = (floatx4){0.f, 0.f, 0.f, 0.f};

#pragma unroll
    for (int kt = 0; kt < 8; ++kt) {
        const bf16* Abase = (kt < 4) ? Aagg : Hroot;
        const int k0 = (kt & 3) * 32 + quad * 8;
        short8 afrag = (short8){0, 0, 0, 0, 0, 0, 0, 0};
        if (rowok) afrag = *(const short8*)(Abase + (size_t)row_a * 128 + k0);
#pragma unroll
        for (int ct = 0; ct < 8; ++ct) {
            const short8 bfrag = *(const short8*)(wsw + (size_t)((kt * 8 + ct) * 64 + lane) * 8);
            acc[ct] = __builtin_amdgcn_mfma_f32_16x16x32_bf16(afrag, bfrag, acc[ct], 0, 0, 0);
        }
    }

    const int row_o = blockIdx.x * 64 + wave * 16 + quad * 4;
#pragma unroll
    for (int ct = 0; ct < 8; ++ct) {
        const int colc = ct * 16 + l15;
        const float bv = bias[colc];
#pragma unroll
        for (int r = 0; r < 4; ++r) {
            const int row = row_o + r;
            if (row < M) {
                float v = acc[ct][r] + bv;
                if (RELU) v = fmaxf(v, 0.f);
                if constexpr (sizeof(OT) == 2)
                    ((bf16*)out)[(size_t)row * 128 + colc] = __float2bfloat16(v);
                else
                    ((float*)out)[(size_t)row * 128 + colc] = v;
            }
        }
    }
}

// ---------------- launch ----------------

extern "C" void kernel_launch(void* const* d_in, const int* in_sizes, int n_in,
                              void* d_out, int out_size, void* d_ws, size_t ws_size,
                              hipStream_t stream) {
    const float* x       = (const float*)d_in[0];
    const int*   ei      = (const int*)d_in[1];
    const float* w_rel1  = (const float*)d_in[2];
    const float* w_root1 = (const float*)d_in[3];
    const float* b1      = (const float*)d_in[4];
    const float* w_rel2  = (const float*)d_in[5];
    const float* w_root2 = (const float*)d_in[6];
    const float* b2      = (const float*)d_in[7];
    const float* w_rel3  = (const float*)d_in[8];
    const float* w_root3 = (const float*)d_in[9];
    const float* b3      = (const float*)d_in[10];
    float* out = (float*)d_out;

    const int N = in_sizes[0] / 128;
    const int E = in_sizes[1] / 2;
    const int* src = ei;
    const int* dst = ei + E;

    // workspace layout (~84 MB)
    char* w = (char*)d_ws;
    auto alloc = [&](size_t bytes) {
        char* p = w;
        w += (bytes + 255) & ~(size_t)255;
        return p;
    };
    int*  col  = (int*)alloc((size_t)E * 4);            // 6.4 MB
    int*  rp   = (int*)alloc((size_t)(N + 1) * 4);      // 0.4 MB
    bf16* h1   = (bf16*)alloc((size_t)N * 128 * 2);     // 25.6 MB
    bf16* xbf  = (bf16*)alloc((size_t)N * 128 * 2);     // 25.6 MB (reused as h2)
    bf16* agg  = (bf16*)alloc((size_t)N * 128 * 2);     // 25.6 MB
    bf16* wsw1 = (bf16*)alloc(32768 * 2);               // 64 KB
    bf16* wsw2 = (bf16*)alloc(32768 * 2);
    bf16* wsw3 = (bf16*)alloc(32768 * 2);
    bf16* h2   = xbf;       // layer-2 output overwrites xbf (last read: layer-1 gemm)
    // CSR-build scratch aliases buffers written only AFTER the build completes:
    int*  T    = (int*)h1;                  // NB*GB ints (~306 KB) in h1's space
    int*  bsum = (int*)(h1 + 1024 * 1024);  // scan partials, past T
    int*  ebuf = (int*)agg;                 // E ints (6.4 MB) in agg's space

    const int NB = (N + BSZ - 1) / BSZ;        // 391 buckets
    const int GB = (E + CHUNK - 1) / CHUNK;    // 196 sort blocks
    const int nT = NB * GB;                    // 76,636
    const int scanTBlocks = (nT + 255) / 256;  // 300 <= 512

    const int aggBlocks  = (N + 3) / 4;
    const int gemmBlocks = (N + 63) / 64;
    const int cvtBlocks  = (N * 32 + 255) / 256;

    // prep: x -> bf16, weights -> swizzled bf16 B-fragments
    cvt_kernel<<<cvtBlocks, 256, 0, stream>>>(x, xbf, N * 32);
    prep_w_kernel<<<16, 256, 0, stream>>>(w_rel1, w_root1, wsw1);
    prep_w_kernel<<<16, 256, 0, stream>>>(w_rel2, w_root2, wsw2);
    prep_w_kernel<<<16, 256, 0, stream>>>(w_rel3, w_root3, wsw3);

    // CSR by dst: two-level counting sort (no global atomics, no memsets)
    bhist_kernel<<<GB, 256, 0, stream>>>(dst, T, E, NB, GB);
    scan1_kernel<<<scanTBlocks, 256, 0, stream>>>(T, T, bsum, nT);
    scan2_kernel<<<1, 512, 0, stream>>>(bsum, scanTBlocks);
    scan3_kernel<<<scanTBlocks, 256, 0, stream>>>(T, bsum, nT);
    bscatter_kernel<<<GB, 256, 0, stream>>>(src, dst, T, ebuf, E, NB, GB);
    bbuild_kernel<<<NB, 256, 0, stream>>>(T, ebuf, rp, col, E, N, NB, GB);

    // layer 1
    agg_kernel<<<aggBlocks, 256, 0, stream>>>(xbf, rp, col, agg, N);
    mfma_gemm_kernel<true, bf16><<<gemmBlocks, 256, 0, stream>>>(agg, xbf, wsw1, b1, h1, N);
    // layer 2
    agg_kernel<<<aggBlocks, 256, 0, stream>>>(h1, rp, col, agg, N);
    mfma_gemm_kernel<true, bf16><<<gemmBlocks, 256, 0, stream>>>(agg, h1, wsw2, b2, h2, N);
    // layer 3
    agg_kernel<<<aggBlocks, 256, 0, stream>>>(h2, rp, col, agg, N);
    mfma_gemm_kernel<false, float><<<gemmBlocks, 256, 0, stream>>>(agg, h2, wsw3, b3, out, N);
}